// Round 1
// baseline (15650.726 us; speedup 1.0000x reference)
//
#include <hip/hip_runtime.h>
#include <hip/hip_bf16.h>
#include <stdint.h>

#define B_ 128
#define T_ 256
#define IN_ 512
#define H_ 1024
#define G4_ 4096
#define TC_ 64              // time chunk
#define NCHUNK_ (T_ / TC_)

typedef __bf16 bf16x8 __attribute__((ext_vector_type(8)));
typedef float f32x4 __attribute__((ext_vector_type(4)));

#define AS1U(p) ((const __attribute__((address_space(1))) unsigned int*)(p))
#define AS3U(p) ((__attribute__((address_space(3))) unsigned int*)(p))

__device__ __forceinline__ uint16_t f2bf(float f) {
  union { float f; uint32_t u; } v; v.f = f;
  uint32_t r = (v.u + 0x7fffu + ((v.u >> 16) & 1u)) >> 16;
  return (uint16_t)r;
}
__device__ __forceinline__ float bf2f(uint16_t h) {
  union { uint32_t u; float f; } v; v.u = ((uint32_t)h) << 16;
  return v.f;
}
__device__ __forceinline__ float sigmoid_f(float x) {
  return 1.f / (1.f + __expf(-x));
}
__device__ __forceinline__ float tanh_f(float x) {
  x = fminf(15.f, fmaxf(-15.f, x));
  float e = __expf(2.f * x);
  return (e - 1.f) / (e + 1.f);
}

// ---------------- prep kernels ----------------
__global__ void k_f32_to_bf16(const float* __restrict__ src, uint16_t* __restrict__ dst, int n) {
  int i = (blockIdx.x * blockDim.x + threadIdx.x) * 4;
  if (i >= n) return;
  float4 v = *(const float4*)(src + i);
  ushort4 o;
  o.x = f2bf(v.x); o.y = f2bf(v.y); o.z = f2bf(v.z); o.w = f2bf(v.w);
  *(ushort4*)(dst + i) = o;
}

__global__ void k_bias(const float* __restrict__ a, const float* __restrict__ b, float* __restrict__ o) {
  int i = blockIdx.x * blockDim.x + threadIdx.x;
  if (i < G4_) o[i] = a[i] + b[i];
}

// Rearrange w_hh (fp32 [4096][1024]) into per-slice MFMA B-fragments, bf16:
// dst[s][nt][ks][lane][j] = w_hh[1024*nt + 16*s + (lane&15)][ks*32 + (lane>>4)*8 + j]
__global__ void k_whh_frag(const float* __restrict__ whh, uint16_t* __restrict__ dst) {
  int tid = blockIdx.x * blockDim.x + threadIdx.x;   // 0..524287
  int lane = tid & 63;
  int ks = (tid >> 6) & 31;
  int nt = (tid >> 11) & 3;
  int s  = tid >> 13;
  int row = nt * 1024 + s * 16 + (lane & 15);
  int col = ks * 32 + ((lane >> 4) << 3);
  const float* sp = whh + (size_t)row * H_ + col;
  uint16_t o[8];
  #pragma unroll
  for (int j = 0; j < 8; ++j) o[j] = f2bf(sp[j]);
  uint4 pk;
  __builtin_memcpy(&pk, o, 16);
  *(uint4*)(dst + (size_t)tid * 8) = pk;
}

// ---------------- input-projection GEMM ----------------
// xp[b*TC + tl][n] = sum_k A[b*256 + t0 + tl][k] * W[n][k] + bias[n]   (bf16 out, fp32 acc)
// grid = (64, 32): blockIdx.x = m-tile (2 batch rows x 64 timesteps = 128 rows), blockIdx.y = n-tile
__global__ __launch_bounds__(256, 1) void k_gemm_xp(
    const uint16_t* __restrict__ A, const uint16_t* __restrict__ W,
    const float* __restrict__ bias, uint16_t* __restrict__ xp,
    int K, int t0)
{
  __shared__ __align__(16) uint16_t As[128 * 32];
  __shared__ __align__(16) uint16_t Bs[128 * 32];
  const int tid = threadIdx.x;
  const int l = tid & 63;
  const int w = tid >> 6;
  const int mx = blockIdx.x;
  const int n0 = blockIdx.y * 128;
  const int wm = (w >> 1) * 64;
  const int wn = (w & 1) * 64;

  f32x4 acc[4][4] = {};

  for (int k0 = 0; k0 < K; k0 += 32) {
    __syncthreads();
    #pragma unroll
    for (int it = 0; it < 2; ++it) {
      const int chunk = w * 2 + it;
      const int loff = chunk * 1024 + l * 16;  // byte offset in tile
      const int row = loff >> 6;               // 0..127
      const int colb = loff & 63;
      const int gm = mx * 512 + t0 + ((row >> 6) << 8) + (row & 63);
      const uint16_t* ga = A + (size_t)gm * K + k0 + (colb >> 1);
      __builtin_amdgcn_global_load_lds(AS1U(ga), AS3U((char*)As + chunk * 1024), 16, 0, 0);
      const uint16_t* gb = W + (size_t)(n0 + row) * K + k0 + (colb >> 1);
      __builtin_amdgcn_global_load_lds(AS1U(gb), AS3U((char*)Bs + chunk * 1024), 16, 0, 0);
    }
    __syncthreads();
    bf16x8 af[4], bfr[4];
    #pragma unroll
    for (int i = 0; i < 4; ++i)
      af[i] = *(const bf16x8*)&As[(wm + i * 16 + (l & 15)) * 32 + ((l >> 4) << 3)];
    #pragma unroll
    for (int j = 0; j < 4; ++j)
      bfr[j] = *(const bf16x8*)&Bs[(wn + j * 16 + (l & 15)) * 32 + ((l >> 4) << 3)];
    #pragma unroll
    for (int i = 0; i < 4; ++i) {
      #pragma unroll
      for (int j = 0; j < 4; ++j)
        acc[i][j] = __builtin_amdgcn_mfma_f32_16x16x32_bf16(af[i], bfr[j], acc[i][j], 0, 0, 0);
    }
  }

  #pragma unroll
  for (int i = 0; i < 4; ++i) {
    const int mbase = wm + i * 16 + ((l >> 4) << 2);
    #pragma unroll
    for (int j = 0; j < 4; ++j) {
      const int ncol = n0 + wn + j * 16 + (l & 15);
      const float bv = bias[ncol];
      #pragma unroll
      for (int r = 0; r < 4; ++r) {
        const int mrow = mbase + r;                      // 0..127
        const size_t xrow = (size_t)mx * 128 + mrow;     // == b*TC + tl
        xp[xrow * G4_ + ncol] = f2bf(acc[i][j][r] + bv);
      }
    }
  }
}

// ---------------- persistent LSTM recurrence ----------------
// grid = 256 blocks (1/CU, forced by LDS). 4 batch groups x 64 slice-blocks.
// Block (g,s): samples 32g..32g+31, hidden units 16s..16s+15 (gate rows 1024q+16s+u).
// w_hh slice resident in LDS for the whole chunk; c-state in registers; h exchanged
// via global double buffer + group barrier (device-scope atomics + agent fences).
__global__ __launch_bounds__(256, 1) void k_lstm(
    const uint16_t* __restrict__ whhf, const uint16_t* __restrict__ xp,
    uint16_t* __restrict__ seq, uint16_t* __restrict__ hbuf,
    float* __restrict__ cbuf, unsigned int* __restrict__ ctr, int t0)
{
  __shared__ __align__(16) uint16_t wlds[4 * 32 * 64 * 8];  // 128 KiB
  __shared__ float gates[32][64];                           // 8 KiB
  const int tid = threadIdx.x;
  const int l = tid & 63;
  const int w = tid >> 6;
  const int bid = blockIdx.x;
  const int g = (bid & 7) >> 1;                 // XCD-pair group
  const int s = ((bid >> 3) << 1) | (bid & 1);  // slice 0..63
  const int mt = w >> 1;                        // m-tile (16 samples)
  const int np = w & 1;                         // gate pair

  {
    const uint4* src = (const uint4*)(whhf + (size_t)s * (4 * 32 * 64 * 8));
    uint4* dst = (uint4*)wlds;
    for (int i = tid; i < 4 * 32 * 64; i += 256) dst[i] = src[i];
  }

  const int u = tid & 15;
  const int sp = (tid >> 4) * 2;
  const int b0 = g * 32 + sp;
  float c0 = cbuf[(size_t)b0 * H_ + s * 16 + u];
  float c1 = cbuf[(size_t)(b0 + 1) * H_ + s * 16 + u];

  unsigned int* myctr = ctr + g * 256;  // 1 KiB apart
  const int samp = g * 32 + mt * 16 + (l & 15);
  const uint16_t* bbase = wlds + (2 * np) * (32 * 64 * 8) + l * 8;

  __syncthreads();

  for (int tl = 0; tl < TC_; ++tl) {
    const int par = tl & 1;
    const uint16_t* arow = hbuf + (size_t)par * (B_ * H_) + (size_t)samp * H_ + ((l >> 4) << 3);
    f32x4 a0 = {0.f, 0.f, 0.f, 0.f};
    f32x4 a1 = {0.f, 0.f, 0.f, 0.f};
    #pragma unroll 8
    for (int ks = 0; ks < 32; ++ks) {
      bf16x8 av  = *(const bf16x8*)(arow + ks * 32);
      bf16x8 bv0 = *(const bf16x8*)(bbase + ks * (64 * 8));
      bf16x8 bv1 = *(const bf16x8*)(bbase + 32 * 64 * 8 + ks * (64 * 8));
      a0 = __builtin_amdgcn_mfma_f32_16x16x32_bf16(av, bv0, a0, 0, 0, 0);
      a1 = __builtin_amdgcn_mfma_f32_16x16x32_bf16(av, bv1, a1, 0, 0, 0);
    }
    #pragma unroll
    for (int r = 0; r < 4; ++r) {
      int smp = mt * 16 + ((l >> 4) << 2) + r;
      gates[smp][(2 * np) * 16 + (l & 15)]     = a0[r];
      gates[smp][(2 * np + 1) * 16 + (l & 15)] = a1[r];
    }
    __syncthreads();
    #pragma unroll
    for (int q = 0; q < 2; ++q) {
      const int sm = sp + q;
      const int b = g * 32 + sm;
      const uint16_t* xpr = xp + ((size_t)b * TC_ + tl) * G4_ + s * 16 + u;
      float gi = gates[sm][u]      + bf2f(xpr[0]);
      float gf = gates[sm][16 + u] + bf2f(xpr[1024]);
      float gg = gates[sm][32 + u] + bf2f(xpr[2048]);
      float go = gates[sm][48 + u] + bf2f(xpr[3072]);
      float cc = q ? c1 : c0;
      cc = sigmoid_f(gf) * cc + sigmoid_f(gi) * tanh_f(gg);
      float hh = sigmoid_f(go) * tanh_f(cc);
      if (q) c1 = cc; else c0 = cc;
      uint16_t hb = f2bf(hh);
      hbuf[(size_t)(1 - par) * (B_ * H_) + (size_t)b * H_ + s * 16 + u] = hb;
      seq[((size_t)b * T_ + (t0 + tl)) * H_ + s * 16 + u] = hb;
    }
    __syncthreads();
    if (tid == 0) {
      __threadfence();                 // agent release: flush this XCD's L2
      atomicAdd(myctr, 1u);
      const unsigned int target = 64u * (unsigned)(tl + 1);
      while (__hip_atomic_load(myctr, __ATOMIC_RELAXED, __HIP_MEMORY_SCOPE_AGENT) < target)
        __builtin_amdgcn_s_sleep(2);
      __builtin_amdgcn_fence(__ATOMIC_ACQUIRE, "agent");  // invalidate stale lines
    }
    __syncthreads();
  }
  cbuf[(size_t)b0 * H_ + s * 16 + u] = c0;
  cbuf[(size_t)(b0 + 1) * H_ + s * 16 + u] = c1;
}

// ---------------- MLP head ----------------
__global__ __launch_bounds__(256) void k_mlp(
    const uint16_t* __restrict__ seq2,
    const float* __restrict__ w1, const float* __restrict__ b1,
    const float* __restrict__ w2, const float* __restrict__ b2,
    float* __restrict__ out)
{
  __shared__ float hv[H_];
  __shared__ float part[32][8];
  __shared__ float hid[32];
  const int b = blockIdx.x, tid = threadIdx.x;
  const uint16_t* hrow = seq2 + ((size_t)b * T_ + (T_ - 1)) * H_;
  for (int i = tid; i < H_; i += 256) hv[i] = bf2f(hrow[i]);
  __syncthreads();
  const int j = tid >> 3, p = tid & 7;
  float sum = 0.f;
  const float* wr = w1 + (size_t)j * H_ + p * 128;
  const float* hp = hv + p * 128;
  for (int k = 0; k < 128; ++k) sum += wr[k] * hp[k];
  part[j][p] = sum;
  __syncthreads();
  if (tid < 32) {
    float s2 = 0.f;
    #pragma unroll
    for (int pp = 0; pp < 8; ++pp) s2 += part[tid][pp];
    hid[tid] = fmaxf(s2 + b1[tid], 0.f);
  }
  __syncthreads();
  if (tid < 10) {
    float o = b2[tid];
    #pragma unroll
    for (int jj = 0; jj < 32; ++jj) o += hid[jj] * w2[tid * 32 + jj];
    out[b * 10 + tid] = o;
  }
}

// ---------------- launch ----------------
extern "C" void kernel_launch(void* const* d_in, const int* in_sizes, int n_in,
                              void* d_out, int out_size, void* d_ws, size_t ws_size,
                              hipStream_t stream)
{
  const float* x = (const float*)d_in[0];
  const float* w_ih[3] = {(const float*)d_in[1], (const float*)d_in[5], (const float*)d_in[9]};
  const float* w_hh[3] = {(const float*)d_in[2], (const float*)d_in[6], (const float*)d_in[10]};
  const float* b_ih[3] = {(const float*)d_in[3], (const float*)d_in[7], (const float*)d_in[11]};
  const float* b_hh[3] = {(const float*)d_in[4], (const float*)d_in[8], (const float*)d_in[12]};
  const float* w1 = (const float*)d_in[13];
  const float* b1 = (const float*)d_in[14];
  const float* w2 = (const float*)d_in[15];
  const float* b2 = (const float*)d_in[16];
  float* out = (float*)d_out;

  char* ws = (char*)d_ws;
  size_t off = 0;
  auto alloc = [&](size_t bytes) {
    char* p = ws + off;
    off += (bytes + 255) & ~(size_t)255;
    return p;
  };
  uint16_t* XBF  = (uint16_t*)alloc((size_t)B_ * T_ * IN_ * 2);
  uint16_t* WIH0 = (uint16_t*)alloc((size_t)G4_ * IN_ * 2);
  uint16_t* WIH1 = (uint16_t*)alloc((size_t)G4_ * H_ * 2);
  uint16_t* WIH2 = (uint16_t*)alloc((size_t)G4_ * H_ * 2);
  float*    BIAS = (float*)alloc((size_t)3 * G4_ * 4);
  uint16_t* WHHF = (uint16_t*)alloc((size_t)3 * G4_ * H_ * 2);
  uint16_t* XP   = (uint16_t*)alloc((size_t)B_ * TC_ * G4_ * 2);
  uint16_t* SEQ  = (uint16_t*)alloc((size_t)B_ * T_ * H_ * 2);
  uint16_t* HBUF = (uint16_t*)alloc((size_t)2 * B_ * H_ * 2);
  float*    CBUF = (float*)alloc((size_t)B_ * H_ * 4);
  unsigned int* CTR = (unsigned int*)alloc((size_t)3 * NCHUNK_ * 4096);

  hipMemsetAsync(CTR, 0, (size_t)3 * NCHUNK_ * 4096, stream);

  int n;
  n = B_ * T_ * IN_;
  k_f32_to_bf16<<<n / 4 / 256, 256, 0, stream>>>(x, XBF, n);
  n = G4_ * IN_;
  k_f32_to_bf16<<<n / 4 / 256, 256, 0, stream>>>(w_ih[0], WIH0, n);
  n = G4_ * H_;
  k_f32_to_bf16<<<n / 4 / 256, 256, 0, stream>>>(w_ih[1], WIH1, n);
  k_f32_to_bf16<<<n / 4 / 256, 256, 0, stream>>>(w_ih[2], WIH2, n);
  for (int li = 0; li < 3; ++li)
    k_bias<<<16, 256, 0, stream>>>(b_ih[li], b_hh[li], BIAS + li * G4_);
  for (int li = 0; li < 3; ++li)
    k_whh_frag<<<2048, 256, 0, stream>>>(w_hh[li], WHHF + (size_t)li * G4_ * H_);

  const uint16_t* seq_in[3] = {XBF, SEQ, SEQ};
  const uint16_t* wih[3] = {WIH0, WIH1, WIH2};
  const int Ks[3] = {IN_, H_, H_};

  for (int li = 0; li < 3; ++li) {
    hipMemsetAsync(HBUF, 0, (size_t)2 * B_ * H_ * 2, stream);
    hipMemsetAsync(CBUF, 0, (size_t)B_ * H_ * 4, stream);
    for (int c = 0; c < NCHUNK_; ++c) {
      dim3 grid(64, 32);
      k_gemm_xp<<<grid, 256, 0, stream>>>(seq_in[li], wih[li], BIAS + li * G4_, XP,
                                          Ks[li], c * TC_);
      unsigned int* ctr_lc = (unsigned int*)((char*)CTR + (size_t)(li * NCHUNK_ + c) * 4096);
      k_lstm<<<256, 256, 0, stream>>>(WHHF + (size_t)li * G4_ * H_, XP, SEQ, HBUF,
                                      CBUF, ctr_lc, c * TC_);
    }
  }
  k_mlp<<<B_, 256, 0, stream>>>(SEQ, w1, b1, w2, b2, out);
}